// Round 12
// baseline (378.967 us; speedup 1.0000x reference)
//
#include <hip/hip_runtime.h>
#include <math.h>

#define PI_F 3.14159265358979323846f

typedef __bf16  bf16x8  __attribute__((ext_vector_type(8)));
typedef __bf16  bf16x4  __attribute__((ext_vector_type(4)));
typedef float   floatx4 __attribute__((ext_vector_type(4)));

// tanh-gelu via fast exp: 0.5x(1+tanh(y)) == x*sigmoid(2y)
__device__ __forceinline__ float gelu_tanh(float x){
  float z = 1.5957691216f*x + 0.07135481283f*x*x*x;
  return x / (1.f + __expf(-z));
}

// async global->LDS 16B per lane; LDS dest = wave-uniform base + lane*16
__device__ __forceinline__ void gl_lds16(const void* g, void* l){
  __builtin_amdgcn_global_load_lds(
      (const __attribute__((address_space(1))) void*)(uintptr_t)g,
      (__attribute__((address_space(3))) void*)(uintptr_t)l,
      16, 0, 0);
}

// ---------------- prep2: zfill (bf16x8) + wcvt cm_w2 + wlat + stat-zero + modulation tables ----------------
// zfill slice vectorized: 16B stores, 1440 -> 180 blocks (grid thresholds shifted accordingly).
__global__ __launch_bounds__(256) void prep2_k(const float* __restrict__ w2in,
                                               __bf16* __restrict__ wt2,
                                               __bf16* __restrict__ kbuf,
                                               const float* __restrict__ lat,
                                               float* __restrict__ wlat,
                                               float* __restrict__ gstat,
                                               const float* __restrict__ lon,
                                               const float* __restrict__ flong,
                                               const float* __restrict__ flat,
                                               const float* __restrict__ wlong,
                                               const float* __restrict__ wlatm,
                                               float* __restrict__ modul,
                                               float* __restrict__ modua){
  __shared__ float basis[64];
  int b = blockIdx.x, t = threadIdx.x;
  if(b < 180){
    // 180*256*8 = 368640 exactly
    bf16x8 z;
    #pragma unroll
    for(int e=0;e<8;e++) z[e] = (__bf16)0.f;
    *(bf16x8*)&kbuf[(size_t)(b*256 + t)*8] = z;
  } else if(b < 3252){
    int idx = (b-180)*256 + t;   // 786432 total
    int n = idx >> 10, k = idx & 1023;      // wt2[n][k] = w2[k][n], N=768,K=1024
    wt2[idx] = (__bf16)w2in[(size_t)k*768 + n];
  } else if(b == 3252){
    gstat[t] = 0.f; gstat[t+256] = 0.f;      // zero 8x32x2 replica stats
    if(t < 91) wlat[t] = cosf(lat[t]);
    __syncthreads();
    if(t == 0){
      float dlat = lat[1]-lat[0];
      float s4 = sinf(dlat*0.25f);
      float pw = s4*s4 / sinf(dlat*0.5f);
      if(wlat[0]  < 0.001f) wlat[0]  = pw;
      if(wlat[90] < 0.001f) wlat[90] = pw;
    }
  } else {
    // modulation tables, transposed out[(h*192+d)][m]
    int b2 = b - 3253;
    const float* coord; const float* freqs; const float* W; float* out;
    int h, m, nm, nk, periodic;
    if(b2 < 1440){ h=b2/180; m=b2%180; nm=180; nk=64; periodic=1; coord=lon; freqs=flong; W=wlong; out=modul; }
    else         { int b3=b2-1440; h=b3/91; m=b3%91; nm=91; nk=32; periodic=0; coord=lat; freqs=flat; W=wlatm; out=modua; }
    float dist = fabsf(coord[m] - coord[0]);
    if(periodic && dist > PI_F) dist = 2.f*PI_F - dist;
    float d = dist + 1e-5f;
    if(t < nk) basis[t] = 0.7978845608028654f * sinf(freqs[t]*d/PI_F) / d;
    __syncthreads();
    if(t < 192){
      float s=0.f;
      for(int k=0;k<nk;k++) s += basis[k]*W[(size_t)(k*8+h)*192+t];
      out[((size_t)h*192 + t)*nm + m] = s;
    }
  }
}

// ---------------- GN1 stats (8-replica atomics) + bf16 cast of u_src ----------------
// float4 loads / bf16x4 stores: each thread owns 4 fixed channels c4=(t&63)*4, 4 rows per
// chunk-iter (sub = t>>6). Group g = c4>>3 = (t&63)>>1: all 4 channels of a thread share
// one group -> per-thread fold, then 8-thread LDS fold, then replica atomics (count/group
// unchanged: 16380 rows x 8 ch = 131040).
__global__ __launch_bounds__(256) void gn1cast_k(const float* __restrict__ x,
                                                 __bf16* __restrict__ xa,
                                                 float* __restrict__ gstat, int nchunk){
  int t = threadIdx.x;
  int sub = t >> 6;          // 0..3 row within 4-row chunk
  int c4  = (t & 63) * 4;    // channel base (fixed per thread)
  float s0=0.f,s1=0.f,s2=0.f,s3=0.f, q0=0.f,q1=0.f,q2=0.f,q3=0.f;
  for(int p4 = blockIdx.x; p4 < nchunk; p4 += gridDim.x){
    size_t row = (size_t)p4*4 + sub;
    floatx4 v = *(const floatx4*)&x[row*256 + c4];
    bf16x4 o;
    o[0]=(__bf16)v[0]; o[1]=(__bf16)v[1]; o[2]=(__bf16)v[2]; o[3]=(__bf16)v[3];
    *(bf16x4*)&xa[row*256 + c4] = o;
    s0+=v[0]; q0+=v[0]*v[0];
    s1+=v[1]; q1+=v[1]*v[1];
    s2+=v[2]; q2+=v[2]*v[2];
    s3+=v[3]; q3+=v[3]*v[3];
  }
  __shared__ float ss[256], sq[256];
  ss[t] = s0+s1+s2+s3;
  sq[t] = q0+q1+q2+q3;
  __syncthreads();
  if(t < 32){
    int g = t;
    float A=0.f, Q=0.f;
    #pragma unroll
    for(int k=0;k<4;k++){
      A += ss[k*64 + 2*g] + ss[k*64 + 2*g + 1];
      Q += sq[k*64 + 2*g] + sq[k*64 + 2*g + 1];
    }
    float* dst = gstat + (blockIdx.x&7)*64 + g*2;
    atomicAdd(dst+0, A);
    atomicAdd(dst+1, Q);
  }
}

// ---------------- fold GN1 into W1 (folds the replica stats itself) ----------------
__global__ __launch_bounds__(256) void w1fix_k(const float* __restrict__ w1,
                                               const float* __restrict__ b1,
                                               const float* __restrict__ gstat,
                                               const float* __restrict__ gw,
                                               const float* __restrict__ gb,
                                               __bf16* __restrict__ wt1,
                                               float* __restrict__ b1p){
  __shared__ float st[64];
  int n = blockIdx.x, c = threadIdx.x;
  if(c < 64){
    float v = 0.f;
    #pragma unroll
    for(int k=0;k<8;k++) v += gstat[k*64 + c];
    st[c] = v;
  }
  __syncthreads();
  int g = c>>3;
  float m = st[g*2+0]*(1.f/131040.f);
  float var = st[g*2+1]*(1.f/131040.f) - m*m;
  float r = rsqrtf(var+1e-5f);
  float s = r*gw[c];
  float t = gb[c] - m*s;
  float w = w1[(size_t)c*1024 + n];
  wt1[(size_t)n*256 + c] = (__bf16)(s*w);
  __shared__ float red[256];
  red[c] = t*w; __syncthreads();
  for(int stp=128; stp>0; stp>>=1){ if(c<stp) red[c]+=red[c+stp]; __syncthreads(); }
  if(c==0) b1p[n] = b1[n] + red[0];
}

// ---------------- fold GN2 into mh_w ----------------
__global__ __launch_bounds__(256) void w3fix_k(const float* __restrict__ mhw,
                                               const float* __restrict__ part2,
                                               const float* __restrict__ gw,
                                               const float* __restrict__ gb,
                                               __bf16* __restrict__ wt3,
                                               float* __restrict__ b3){
  __shared__ float st[16];
  __shared__ float ps[256], pq[256];
  int n = blockIdx.x, t = threadIdx.x;
  {
    int g = t & 7, ch = t >> 3;
    float s=0.f,q=0.f;
    for(int i=ch; i<91; i+=32){
      s += part2[(g*91+i)*2+0];
      q += part2[(g*91+i)*2+1];
    }
    ps[t]=s; pq[t]=q;
    __syncthreads();
    if(t<8){
      float a=0.f,bq=0.f;
      #pragma unroll
      for(int c=0;c<32;c++){ a+=ps[c*8+t]; bq+=pq[c*8+t]; }
      float m = a*(1.f/1048320.f);
      float v = bq*(1.f/1048320.f) - m*m;
      st[t*2+0]=m; st[t*2+1]=rsqrtf(v+1e-5f);
    }
    __syncthreads();
  }
  float bp=0.f;
  #pragma unroll
  for(int l=0;l<2;l++){
    int cc = t + l*256;
    int g = cc>>6;
    float m = st[g*2+0], r = st[g*2+1];
    float s = r*gw[cc];
    float tt = gb[cc] - m*s;
    float w = mhw[(size_t)cc*256 + n];
    wt3[(size_t)n*512 + cc] = (__bf16)(s*w);
    bp += tt*w;
  }
  __shared__ float red[256];
  red[t]=bp; __syncthreads();
  for(int stp=128;stp>0;stp>>=1){ if(t<stp) red[t]+=red[t+stp]; __syncthreads(); }
  if(t==0) b3[n]=red[0];
}

// ---------------- MFMA bf16 GEMM: 512 thr / 8 waves, BK=32, 3-buffer depth-2 TWO-BARRIER pipeline ----------------
// (structure validated round 8: B1 = counted-vmcnt DMA-landed; B2 = lgkmcnt(0) reads-executed)
template<int ACT, int OUTMODE>
__global__ __launch_bounds__(512) void gemm_ld(const __bf16* __restrict__ A,
                                               const __bf16* __restrict__ Bt,
                                               const float* __restrict__ bias,
                                               void* __restrict__ Cp,
                                               __bf16* __restrict__ VB,
                                               __bf16* __restrict__ UM,
                                               int M, int N, int K)
{
  __shared__ __bf16 smem[24576];   // 3 x (As[128][32] | Bs[128][32]) = 48KB; C-stage reuses 32KB
  __bf16* Asb = smem;              // [3][128][32]
  __bf16* Bsb = smem + 12288;      // [3][128][32]
  const int tid  = threadIdx.x;
  const int lane = tid & 63, wave = tid >> 6;
  const int row0 = blockIdx.x*128, col0 = blockIdx.y*128;
  const int lrow = lane >> 2;                       // 16 rows per wave-load
  const int csw  = ((lane&3) ^ ((lane>>3)&3)) * 8;  // swizzled source chunk
  const int wr = (wave >> 2)*64, wc = (wave & 3)*32;
  const int m16 = lane & 15, quad = lane >> 4;
  const int pa = (quad ^ ((m16>>1)&3)) * 8;         // swizzled read chunk

  const __bf16* Ag = A  + (size_t)(row0 + wave*16 + lrow)*K + csw;
  const __bf16* Bg = Bt + (size_t)(col0 + wave*16 + lrow)*K + csw;

  floatx4 acc[4][2];
  #pragma unroll
  for(int i=0;i<4;i++)
    #pragma unroll
    for(int j=0;j<2;j++) acc[i][j] = (floatx4)0.f;

  const int kiters = K >> 5;
  // prologue: issue iters 0 and 1 into buffers 0,1 (2 loads/thread each)
  gl_lds16(Ag, Asb + wave*512);
  gl_lds16(Bg, Bsb + wave*512);
  Ag += 32; Bg += 32;
  if(kiters > 1){
    gl_lds16(Ag, Asb + 4096 + wave*512);
    gl_lds16(Bg, Bsb + 4096 + wave*512);
    Ag += 32; Bg += 32;
  }

  int rd = 0;   // buffer index holding iter kk
  for(int kk=0; kk<kiters; kk++){
    // prefetch iter kk+2 into buf (kk+2)%3 == (kk-1)%3 — safe: B2 of iter kk-1 passed
    if(kk+2 < kiters){
      int pf = rd + 2; if(pf >= 3) pf -= 3;
      gl_lds16(Ag, Asb + pf*4096 + wave*512);
      gl_lds16(Bg, Bsb + pf*4096 + wave*512);
      Ag += 32; Bg += 32;
    }
    // drain only buf-kk's 2 loads; keep newer ones in flight
    if(kk+2 < kiters)      asm volatile("s_waitcnt vmcnt(4)" ::: "memory");
    else if(kk+1 < kiters) asm volatile("s_waitcnt vmcnt(2)" ::: "memory");
    else                   asm volatile("s_waitcnt vmcnt(0)" ::: "memory");
    __builtin_amdgcn_sched_barrier(0);
    __builtin_amdgcn_s_barrier();        // B1: buf kk ready for all waves
    const int cur = rd*4096;
    bf16x8 af[4], bfv[2];
    #pragma unroll
    for(int ti=0;ti<4;ti++) af[ti]  = *(const bf16x8*)&Asb[cur + (wr + ti*16 + m16)*32 + pa];
    #pragma unroll
    for(int tj=0;tj<2;tj++) bfv[tj] = *(const bf16x8*)&Bsb[cur + (wc + tj*16 + m16)*32 + pa];
    #pragma unroll
    for(int ti=0;ti<4;ti++)
      #pragma unroll
      for(int tj=0;tj<2;tj++)
        acc[ti][tj] = __builtin_amdgcn_mfma_f32_16x16x32_bf16(af[ti], bfv[tj], acc[ti][tj], 0,0,0);
    asm volatile("s_waitcnt lgkmcnt(0)" ::: "memory");
    __builtin_amdgcn_sched_barrier(0);
    __builtin_amdgcn_s_barrier();        // B2: all waves' reads of buf kk executed
    rd++; if(rd >= 3) rd = 0;
  }

  if(OUTMODE==0){
    // direct fp32 stores (64B runs per 16-col fragment)
    #pragma unroll
    for(int ti=0;ti<4;ti++){
      #pragma unroll
      for(int reg=0;reg<4;reg++){
        int gr = row0 + wr + ti*16 + quad*4 + reg;
        if(gr >= M) continue;
        #pragma unroll
        for(int tj=0;tj<2;tj++){
          int gc = col0 + wc + tj*16 + m16;
          float v = acc[ti][tj][reg];
          if(bias) v += bias[gc];
          ((float*)Cp)[(size_t)gr*N + gc] = v;
        }
      }
    }
  } else {
    // stage bf16 tile in smem (K-loop buffers dead after final B2; vmcnt/lgkmcnt drained)
    #pragma unroll
    for(int ti=0;ti<4;ti++){
      #pragma unroll
      for(int reg=0;reg<4;reg++){
        int r = wr + ti*16 + quad*4 + reg;
        #pragma unroll
        for(int tj=0;tj<2;tj++){
          int c = wc + tj*16 + m16;
          float v = acc[ti][tj][reg];
          if(bias) v += bias[col0 + c];
          if(ACT==1) v = gelu_tanh(v);
          smem[r*128 + c] = (__bf16)v;
        }
      }
    }
    __syncthreads();
    if(OUTMODE==1){
      for(int idx=tid; idx<2048; idx+=512){
        int r = idx>>4, ch = (idx&15)*8;
        int gr = row0 + r;
        if(gr < M)
          *(bf16x8*)((__bf16*)Cp + (size_t)gr*N + col0 + ch) = *(const bf16x8*)&smem[r*128 + ch];
      }
    } else if(col0 < 512){
      for(int idx=tid; idx<2048; idx+=512){
        int r = idx>>4, ch = (idx&15)*8;
        int gr = row0 + r;
        if(gr < M){
          int jj = gr/180, mm = gr - jj*180;
          int gc = col0 + ch, hh = gc>>6, cc = gc&63;
          *(bf16x8*)&VB[(((size_t)(hh*180+mm)*91)+jj)*64 + cc] = *(const bf16x8*)&smem[r*128 + ch];
        }
      }
    } else {
      for(int idx=tid; idx<2048; idx+=512){
        int r = idx>>4, ch = (idx&15)*8;
        int gr = row0 + r;
        if(gr < M)
          *(bf16x8*)&UM[(size_t)gr*256 + (col0-512) + ch] = *(const bf16x8*)&smem[r*128 + ch];
      }
    }
  }
}

// ---------------- merged mean + pooling MLP: 1024 threads/row ----------------
__global__ __launch_bounds__(1024) void mpool_k(
    const __bf16* __restrict__ um, const float* __restrict__ wlat,
    const float* __restrict__ tl_inw, const float* __restrict__ tl_lnw, const float* __restrict__ tl_lnb,
    const float* __restrict__ tl_w1, const float* __restrict__ tl_b1,
    const float* __restrict__ tl_w2, const float* __restrict__ tl_b2,
    const float* __restrict__ ta_inw, const float* __restrict__ ta_lnw, const float* __restrict__ ta_lnb,
    const float* __restrict__ ta_w1, const float* __restrict__ ta_b1,
    const float* __restrict__ ta_w2, const float* __restrict__ ta_b2,
    float* __restrict__ ulsrc, float* __restrict__ uasrc){
  __shared__ float part[32][256];        // 32KB; reused as p4[4][256] + p4b[4][256]
  __shared__ float xs[256], xn[256], g[256];
  __shared__ float wsum[4], wsq[4];
  int b = blockIdx.x, t = threadIdx.x;
  int lane = t & 63, wave = t >> 6;
  const int longp = (b < 180);
  int r = longp ? b : b-180;

  const float* inw = longp ? tl_inw : ta_inw;
  const float* lnw = longp ? tl_lnw : ta_lnw;
  const float* lnb = longp ? tl_lnb : ta_lnb;
  const float* w1  = longp ? tl_w1  : ta_w1;
  const float* b1  = longp ? tl_b1  : ta_b1;
  const float* w2  = longp ? tl_w2  : ta_w2;
  const float* b2  = longp ? tl_b2  : ta_b2;
  float*       out = longp ? ulsrc  : uasrc;

  // ---- mean phase: 32-way slice of reduction axis, bf16x8 (16B) loads ----
  int vec = (t & 31) * 8;   // channel-chunk base
  int sub = t >> 5;         // 0..31 slice
  float acc[8] = {0.f,0.f,0.f,0.f,0.f,0.f,0.f,0.f};
  if(longp){
    for(int j=sub; j<91; j+=32){
      bf16x8 v = *(const bf16x8*)&um[((size_t)(j*180+b))*256 + vec];
      #pragma unroll
      for(int e=0;e<8;e++) acc[e] += (float)v[e];
    }
  } else {
    const __bf16* base = um + (size_t)r*180*256;
    for(int m=sub; m<180; m+=32){
      bf16x8 v = *(const bf16x8*)&base[(size_t)m*256 + vec];
      #pragma unroll
      for(int e=0;e<8;e++) acc[e] += (float)v[e];
    }
  }
  #pragma unroll
  for(int e=0;e<8;e++) part[sub][vec+e] = acc[e];
  __syncthreads();
  if(t < 256){
    float s = 0.f;
    #pragma unroll
    for(int k=0;k<32;k++) s += part[k][t];
    xs[t] = s * (longp ? (1.0f/91.0f) : (1.0f/180.0f));
  }
  __syncthreads();   // xs ready; part reads done -> p4 reuse safe

  // ---- phase y: y = xs @ inw, 4-way c-split ----
  float* p4  = &part[0][0];        // [4][256]
  float* p4b = &part[4][0];        // [4][256]
  int q = t >> 8;                  // 0..3 c-chunk
  int o = t & 255;                 // output index
  {
    float yp = 0.f;
    #pragma unroll 8
    for(int c=q*64; c<q*64+64; c++) yp += xs[c]*inw[c*256+o];
    p4[q*256+o] = yp;
  }
  __syncthreads();

  // ---- LN (threads 0..255, shuffle butterfly) ----
  if(t < 256){
    float y = p4[t] + p4[256+t] + p4[512+t] + p4[768+t];
    if(!longp) y *= wlat[r];
    float s = y, qq = y*y;
    #pragma unroll
    for(int off=32; off>0; off>>=1){
      s  += __shfl_xor(s,  off, 64);
      qq += __shfl_xor(qq, off, 64);
    }
    if(lane==0){ wsum[wave]=s; wsq[wave]=qq; }
    xn[t] = y;   // stash y; finish after stats visible
  }
  __syncthreads();
  if(t < 256){
    float s  = wsum[0]+wsum[1]+wsum[2]+wsum[3];
    float qq = wsq[0]+wsq[1]+wsq[2]+wsq[3];
    float m  = s*(1.f/256.f);
    float var = qq*(1.f/256.f) - m*m;
    xn[t] = (xn[t]-m)*rsqrtf(var+1e-5f)*lnw[t] + lnb[t];
  }
  __syncthreads();

  // ---- phase h: s1,s2 = xn @ w1 (512 outs), 4-way c-split ----
  {
    float h1 = 0.f, h2 = 0.f;
    #pragma unroll 8
    for(int c=q*64; c<q*64+64; c++){
      float xv = xn[c];
      h1 += xv*w1[c*512+o];
      h2 += xv*w1[c*512+256+o];
    }
    p4[q*256+o]  = h1;
    p4b[q*256+o] = h2;
  }
  __syncthreads();
  if(t < 256){
    float s1 = p4[t]+p4[256+t]+p4[512+t]+p4[768+t] + b1[t];
    float s2 = p4b[t]+p4b[256+t]+p4b[512+t]+p4b[768+t] + b1[256+t];
    g[t] = gelu_tanh(s1)*s2;
  }
  __syncthreads();

  // ---- phase o: out = g @ w2, 4-way c-split ----
  {
    float op = 0.f;
    #pragma unroll 8
    for(int c=q*64; c<q*64+64; c++) op += g[c]*w2[c*256+o];
    p4[q*256+o] = op;
  }
  __syncthreads();
  if(t < 256)
    out[r*256+t] = p4[t]+p4[256+t]+p4[512+t]+p4[768+t] + b2[t];
}

// ---------------- k-projection, r-tiled: out[j][r0..r0+6] (28B runs per thread) ----------------
__global__ __launch_bounds__(256) void kproj_k(const float* __restrict__ ulsrc,
                                               const float* __restrict__ uasrc,
                                               const float* __restrict__ wlong,
                                               const float* __restrict__ wlatk,
                                               float* __restrict__ klkl,
                                               float* __restrict__ klka){
  int rt = blockIdx.x, jc = blockIdx.y, t = threadIdx.x;
  const int longp = (rt < 26);
  int r0 = (longp ? rt : rt-26) * 7;
  int R  = longp ? 180 : 91;
  int nr = R - r0; if(nr > 7) nr = 7;
  const float* X = longp ? ulsrc : uasrc;
  const float* W = longp ? wlong : wlatk;
  float* out = longp ? klkl : klka;
  __shared__ float xs[7][256];
  for(int idx=t; idx<nr*256; idx+=256)
    xs[idx>>8][idx&255] = X[(size_t)(r0 + (idx>>8))*256 + (idx&255)];
  __syncthreads();
  int j = jc*256 + t;
  float acc[7] = {0.f,0.f,0.f,0.f,0.f,0.f,0.f};
  const float* wp = W + j;
  #pragma unroll 4
  for(int c=0; c<256; c++){
    float wv = wp[(size_t)c*1536];
    #pragma unroll
    for(int rr=0; rr<7; rr++) acc[rr] += xs[rr][c]*wv;
  }
  float* op = out + (size_t)j*R + r0;
  for(int rr=0; rr<nr; rr++) op[rr] = acc[rr];
}

// ---------------- merged low-rank kernels, 2 query-rows per block (shared kp stream) ----------------
__global__ __launch_bounds__(256) void lrk2_k(const float* __restrict__ qlong,
                                              const float* __restrict__ qlat,
                                              const float* __restrict__ klkl,
                                              const float* __restrict__ klka,
                                              const float* __restrict__ modul,
                                              const float* __restrict__ modua,
                                              const float* __restrict__ wlat,
                                              __bf16* __restrict__ kbg,
                                              __bf16* __restrict__ kbl){
  int b = blockIdx.x, t = threadIdx.x;
  const float* qry; const float* kt; const float* mt; const float* js; __bf16* out;
  int h, i0, n, pitch; float scale;
  if(b < 720){ h=b/90; int p=b%90; i0=2*p; n=180; pitch=192; qry=qlong; kt=klkl; mt=modul; js=nullptr; out=kbg; scale=2.f*PI_F/180.f; }
  else        { int b2=b-720; h=b2/46; int p=b2%46; i0=2*p; n=91; pitch=96; qry=qlat; kt=klka; mt=modua; js=wlat; out=kbl; scale=PI_F/91.f; }
  int i1 = i0+1;
  const int has1 = (i1 < n);
  int i1c = has1 ? i1 : i0;
  __shared__ float qs[2][192];
  for(int idx=t; idx<384; idx+=256){
    int row = (idx >= 192);
    int d = idx - row*192;
    int ii = row ? i1c : i0;
    qs[row][d] = qry[(size_t)ii*1536 + h*192 + d];
  }
  __syncthreads();
  int j = t;
  if(j < n){
    int m0 = abs(i0 - j);
    int m1 = abs(i1c - j);
    const float* kp = kt + (size_t)h*192*n;
    const float* mp = mt + (size_t)h*192*n;
    float s0=0.f, s1=0.f;
    #pragma unroll 4
    for(int d=0; d<192; d++){
      float kv = kp[(size_t)d*n + j];
      s0 += qs[0][d]*kv*mp[(size_t)d*n + m0];
      s1 += qs[1][d]*kv*mp[(size_t)d*n + m1];
    }
    s0 = (s0>=0.f) ? s0 : 0.2f*s0;
    if(js) s0 *= js[j];
    out[((size_t)h*pitch + i0)*pitch + j] = (__bf16)(s0*scale);
    if(has1){
      s1 = (s1>=0.f) ? s1 : 0.2f*s1;
      if(js) s1 *= js[j];
      out[((size_t)h*pitch + i1)*pitch + j] = (__bf16)(s1*scale);
    }
  }
}

// ---------------- apply1 MFMA: per (h,m): C[91,64] = klat[h](91x91) @ V(91x64) ----------------
__global__ __launch_bounds__(256) void apply1_mfma(const __bf16* __restrict__ Kl,
                                                   const __bf16* __restrict__ vbf,
                                                   __bf16* __restrict__ u1){
  int h = blockIdx.x / 180, m = blockIdx.x % 180;
  __shared__ __bf16 vst[64][104];           // 6656 elems; reused as ost[91][72]=6552
  int t = threadIdx.x;
  const __bf16* src = vbf + ((size_t)(h*180+m)*91)*64;
  for(int idx=t; idx<91*64; idx+=256){
    int j = idx>>6, c = idx&63;
    vst[c][j] = src[idx];
  }
  for(int idx=t; idx<64*13; idx+=256){
    int c = idx/13, j = 91 + idx - (idx/13)*13;
    vst[c][j] = (__bf16)0.f;
  }
  __syncthreads();
  int lane = t & 63, wave = t>>6;
  int m16 = lane & 15, quad = lane>>4;
  floatx4 acc[6];
  #pragma unroll
  for(int i=0;i<6;i++) acc[i]=(floatx4)0.f;
  const __bf16* Ab = Kl + (size_t)h*96*96;
  #pragma unroll
  for(int kc=0; kc<3; kc++){
    bf16x8 bfrag = *(const bf16x8*)&vst[wave*16 + m16][kc*32 + quad*8];
    #pragma unroll
    for(int ti=0;ti<6;ti++){
      bf16x8 afrag = *(const bf16x8*)&Ab[(size_t)(ti*16+m16)*96 + kc*32 + quad*8];
      acc[ti] = __builtin_amdgcn_mfma_f32_16x16x32_bf16(afrag, bfrag, acc[ti], 0,0,0);
    }
  }
  __syncthreads();                          // vst reads done; reuse as ost
  __bf16* ost = &vst[0][0];
  int c = wave*16 + m16;
  #pragma unroll
  for(int ti=0;ti<6;ti++){
    #pragma unroll
    for(int reg=0;reg<4;reg++){
      int i = ti*16 + quad*4 + reg;
      if(i<91) ost[i*72 + c] = (__bf16)acc[ti][reg];
    }
  }
  __syncthreads();
  __bf16* dst = u1 + (((size_t)(h*91)*180)+m)*64;
  for(int idx=t; idx<91*8; idx+=256){
    int i = idx>>3, cc = idx&7;
    *(bf16x8*)(dst + (size_t)i*180*64 + cc*8) = *(const bf16x8*)&ost[i*72 + cc*8];
  }
}

// ---------------- apply2 MFMA: A2 bf16 [pos][512] via staged 128B stores + GN2 partials ----------------
__global__ __launch_bounds__(256) void apply2_mfma(const __bf16* __restrict__ Kg,
                                                   const __bf16* __restrict__ u1,
                                                   __bf16* __restrict__ a2,
                                                   float* __restrict__ part2){
  int h = blockIdx.x / 91, i = blockIdx.x % 91;
  __shared__ __bf16 vst[64][208];           // 13312 elems; reused as ost[180][72]=12960
  __shared__ float rs[256], rq[256];
  int t = threadIdx.x;
  const __bf16* src = u1 + ((size_t)(h*91+i)*180)*64;
  for(int idx=t; idx<180*64; idx+=256){
    int m = idx>>6, c = idx&63;
    vst[c][m] = src[idx];
  }
  for(int idx=t; idx<64*28; idx+=256){
    int c = idx/28, m = 180 + idx - (idx/28)*28;
    vst[c][m] = (__bf16)0.f;
  }
  __syncthreads();
  int lane = t&63, wave = t>>6;
  int m16 = lane&15, quad = lane>>4;
  floatx4 acc[12];
  #pragma unroll
  for(int l=0;l<12;l++) acc[l]=(floatx4)0.f;
  const __bf16* Ab = Kg + (size_t)h*192*192;
  for(int kc=0; kc<6; kc++){
    bf16x8 bfrag = *(const bf16x8*)&vst[wave*16+m16][kc*32 + quad*8];
    #pragma unroll
    for(int tl=0; tl<12; tl++){
      bf16x8 afrag = *(const bf16x8*)&Ab[(size_t)(tl*16+m16)*192 + kc*32 + quad*8];
      acc[tl] = __builtin_amdgcn_mfma_f32_16x16x32_bf16(afrag, bfrag, acc[tl], 0,0,0);
    }
  }
  __syncthreads();                          // vst reads done; reuse as ost
  __bf16* ost = &vst[0][0];
  int c = wave*16+m16;
  float s=0.f, q=0.f;
  #pragma unroll
  for(int tl=0; tl<12; tl++){
    #pragma unroll
    for(int reg=0; reg<4; reg++){
      int l = tl*16 + quad*4 + reg;
      if(l<180){
        float v = acc[tl][reg];
        ost[l*72 + c] = (__bf16)v;
        s += v; q += v*v;
      }
    }
  }
  rs[t]=s; rq[t]=q;
  __syncthreads();
  for(int st=128; st>0; st>>=1){ if(t<st){ rs[t]+=rs[t+st]; rq[t]+=rq[t+st]; } __syncthreads(); }
  if(t==0){ part2[blockIdx.x*2+0]=rs[0]; part2[blockIdx.x*2+1]=rq[0]; }
  __bf16* dst = a2 + (size_t)i*180*512 + h*64;
  for(int idx=t; idx<180*8; idx+=256){
    int l = idx>>3, cc = idx&7;
    *(bf16x8*)(dst + (size_t)l*512 + cc*8) = *(const bf16x8*)&ost[l*72 + cc*8];
  }
}

// ---------------------------------------------------------------------------
extern "C" void kernel_launch(void* const* d_in, const int* in_sizes, int n_in,
                              void* d_out, int out_size, void* d_ws, size_t ws_size,
                              hipStream_t stream){
  const float* u_src      = (const float*)d_in[0];
  const float* u_lat_qry  = (const float*)d_in[1];
  const float* u_long_qry = (const float*)d_in[2];
  const float* lat = (const float*)d_in[3];
  const float* lon = (const float*)((in_sizes[4]==180)? d_in[4] : d_in[5]);
  const float* cm_gn_w = (const float*)d_in[7];
  const float* cm_gn_b = (const float*)d_in[8];
  const float* cm_w1   = (const float*)d_in[9];
  const float* cm_b1   = (const float*)d_in[10];
  const float* cm_w2   = (const float*)d_in[11];
  const float* cm_b2   = (const float*)d_in[12];
  const float* tl_in_w = (const float*)d_in[13];
  const float* tl_ln_w = (const float*)d_in[14];
  const float* tl_ln_b = (const float*)d_in[15];
  const float* tl_w1   = (const float*)d_in[16];
  const float* tl_b1   = (const float*)d_in[17];
  const float* tl_w2   = (const float*)d_in[18];
  const float* tl_b2   = (const float*)d_in[19];
  const float* ta_in_w = (const float*)d_in[20];
  const float* ta_ln_w = (const float*)d_in[21];
  const float* ta_ln_b = (const float*)d_in[22];
  const float* ta_w1   = (const float*)d_in[23];
  const float* ta_b1   = (const float*)d_in[24];
  const float* ta_w2   = (const float*)d_in[25];
  const float* ta_b2   = (const float*)d_in[26];
  const float* klong_wk= (const float*)d_in[27];
  const float* klat_wk = (const float*)d_in[28];
  const float* pe_long_freq = (const float*)d_in[29];
  const float* pe_long_w    = (const float*)d_in[30];
  const float* pe_lat_freq  = (const float*)d_in[31];
  const float* pe_lat_w     = (const float*)d_in[32];
  const float* mh_gn_w = (const float*)d_in[33];
  const float* mh_gn_b = (const float*)d_in[34];
  const float* mh_w    = (const float*)d_in[35];

  float* ws = (float*)d_ws;
  const size_t OFF_GN1    = 0;          // 512  (8 replicas x 32 groups x {s,q})
  const size_t OFF_WLAT   = 1024;       // 91
  const size_t OFF_ULSRC  = 2048;       // 46080 fp32 [180][256]
  const size_t OFF_UASRC  = 48128;      // 23296 fp32 [91][256]
  const size_t OFF_KLKL   = 102400;     // 276480 fp32 kprojT long [1536][180]
  const size_t OFF_KLKA   = 378880;     // 139776 fp32 kprojT lat  [1536][91]
  const size_t OFF_MODUL  = 518656;     // 276480 fp32 modT long [1536][180]
  const size_t OFF_MODUA  = 795136;     // 139776 fp32 modT lat  [1536][91]
  const size_t OFF_KBL    = 934912;     // bf16 8*96*96   -> 36864 f
  const size_t OFF_KBG    = 971776;     // bf16 8*192*192 -> 147456 f -> ends 1119232
  const size_t OFF_PART2  = 1119232;    // 1456
  const size_t OFF_B1P    = 1120688;    // 1024
  const size_t OFF_B3     = 1121712;    // 256
  const size_t OFF_WT1    = 1122048;    // bf16 [1024][256] -> 131072 f
  const size_t OFF_WT2    = 1253120;    // bf16 [768][1024] -> 393216 f
  const size_t OFF_WT3    = 1646336;    // bf16 [256][512]  -> 65536 f -> ends 1711872
  const size_t OFF_VBF    = 1711872;    // bf16 [8][180][91][64] -> 4193280 f
  const size_t OFF_A2     = 1711872;    // bf16 [16380][512] (reuses VBF post-apply1)
  const size_t OFF_UMID   = 5905152;    // bf16 [16380][256] -> 2096640 f
  const size_t OFF_H1     = 8001792;    // bf16 16380x1024 -> 8386560 f
  const size_t OFF_U1     = 8001792;    // bf16 (reuses H1)
  const size_t OFF_A1     = 16388352;   // bf16 16380x256 -> ends 18484992 (~74 MB)

  const int NPOS = 16380;

  // 1) prep2 (vectorized zfill + wcvt w2 + wlat + stat-zero + modulation tables)
  prep2_k<<<5421,256,0,stream>>>(cm_w2, (__bf16*)(ws+OFF_WT2), (__bf16*)(ws+OFF_KBL),
      lat, ws+OFF_WLAT, ws+OFF_GN1,
      lon, pe_long_freq, pe_lat_freq, pe_long_w, pe_lat_w,
      ws+OFF_MODUL, ws+OFF_MODUA);

  // 2) GN1 stats (replica atomics) + bf16 cast of u_src (float4/bf16x4, 4 rows per chunk)
  gn1cast_k<<<2048,256,0,stream>>>(u_src, (__bf16*)(ws+OFF_A1), ws+OFF_GN1, NPOS/4);

  // 3) fold GN1 into W1 (folds replica stats in-block)
  w1fix_k<<<1024,256,0,stream>>>(cm_w1, cm_b1, ws+OFF_GN1, cm_gn_w, cm_gn_b,
      (__bf16*)(ws+OFF_WT1), ws+OFF_B1P);

  // 4) h1 = gelu(A1 @ W1' + b1')  [16380 x 1024] bf16   (512-thread, 8-wave, 2-barrier pipe)
  gemm_ld<1,1><<<dim3(128,8),512,0,stream>>>((const __bf16*)(ws+OFF_A1),
      (const __bf16*)(ws+OFF_WT1), ws+OFF_B1P, ws+OFF_H1, nullptr, nullptr, NPOS, 1024, 256);

  // 5) u2 = h1 @ W2 + b2: cols<512 -> vbf bf16; cols>=512 -> umid bf16
  gemm_ld<0,2><<<dim3(128,6),512,0,stream>>>((const __bf16*)(ws+OFF_H1),
      (const __bf16*)(ws+OFF_WT2), cm_b2, nullptr, (__bf16*)(ws+OFF_VBF),
      (__bf16*)(ws+OFF_UMID), NPOS, 768, 1024);

  // 6) merged mean + pooling MLPs (1024 threads/row)
  mpool_k<<<271,1024,0,stream>>>((const __bf16*)(ws+OFF_UMID), ws+OFF_WLAT,
      tl_in_w, tl_ln_w, tl_ln_b, tl_w1, tl_b1, tl_w2, tl_b2,
      ta_in_w, ta_ln_w, ta_ln_b, ta_w1, ta_b1, ta_w2, ta_b2,
      ws+OFF_ULSRC, ws+OFF_UASRC);

  // 7) k-projections, r-tiled coalesced stores
  kproj_k<<<dim3(39,6),256,0,stream>>>(ws+OFF_ULSRC, ws+OFF_UASRC, klong_wk, klat_wk,
      ws+OFF_KLKL, ws+OFF_KLKA);

  // 8) merged low-rank kernels (2 rows/block) -> padded bf16
  lrk2_k<<<1088,256,0,stream>>>(u_long_qry, u_lat_qry, ws+OFF_KLKL, ws+OFF_KLKA,
      ws+OFF_MODUL, ws+OFF_MODUA, ws+OFF_WLAT, (__bf16*)(ws+OFF_KBG), (__bf16*)(ws+OFF_KBL));

  // 9) kernel application (MFMA, vectorized epilogues); apply2 emits A2 + GN2 partials
  apply1_mfma<<<8*180,256,0,stream>>>((const __bf16*)(ws+OFF_KBL), (const __bf16*)(ws+OFF_VBF),
      (__bf16*)(ws+OFF_U1));
  apply2_mfma<<<8*91, 256,0,stream>>>((const __bf16*)(ws+OFF_KBG), (const __bf16*)(ws+OFF_U1),
      (__bf16*)(ws+OFF_A2), ws+OFF_PART2);

  // 10) fold GN2 into mh_w, then final projection
  w3fix_k<<<256,256,0,stream>>>(mh_w, ws+OFF_PART2, mh_gn_w, mh_gn_b,
      (__bf16*)(ws+OFF_WT3), ws+OFF_B3);
  gemm_ld<0,0><<<dim3(128,2),512,0,stream>>>((const __bf16*)(ws+OFF_A2),
      (const __bf16*)(ws+OFF_WT3), ws+OFF_B3, (float*)d_out, nullptr, nullptr, NPOS, 256, 512);
}

// Round 13
// 366.489 us; speedup vs baseline: 1.0340x; 1.0340x over previous
//
#include <hip/hip_runtime.h>
#include <math.h>

#define PI_F 3.14159265358979323846f

typedef __bf16  bf16x8  __attribute__((ext_vector_type(8)));
typedef float   floatx4 __attribute__((ext_vector_type(4)));

// tanh-gelu via fast exp: 0.5x(1+tanh(y)) == x*sigmoid(2y)
__device__ __forceinline__ float gelu_tanh(float x){
  float z = 1.5957691216f*x + 0.07135481283f*x*x*x;
  return x / (1.f + __expf(-z));
}

// async global->LDS 16B per lane; LDS dest = wave-uniform base + lane*16
__device__ __forceinline__ void gl_lds16(const void* g, void* l){
  __builtin_amdgcn_global_load_lds(
      (const __attribute__((address_space(1))) void*)(uintptr_t)g,
      (__attribute__((address_space(3))) void*)(uintptr_t)l,
      16, 0, 0);
}

// ---------------- prep2: zfill K buffers + wcvt cm_w2 + wlat + stat-zero + modulation tables ----------------
__global__ __launch_bounds__(256) void prep2_k(const float* __restrict__ w2in,
                                               __bf16* __restrict__ wt2,
                                               __bf16* __restrict__ kbuf,
                                               const float* __restrict__ lat,
                                               float* __restrict__ wlat,
                                               float* __restrict__ gstat,
                                               const float* __restrict__ lon,
                                               const float* __restrict__ flong,
                                               const float* __restrict__ flat,
                                               const float* __restrict__ wlong,
                                               const float* __restrict__ wlatm,
                                               float* __restrict__ modul,
                                               float* __restrict__ modua){
  __shared__ float basis[64];
  int b = blockIdx.x, t = threadIdx.x;
  if(b < 1440){
    int i = b*256 + t;
    if(i < 368640) kbuf[i] = (__bf16)0.f;
  } else if(b < 4512){
    int idx = (b-1440)*256 + t;   // 786432 total
    int n = idx >> 10, k = idx & 1023;      // wt2[n][k] = w2[k][n], N=768,K=1024
    wt2[idx] = (__bf16)w2in[(size_t)k*768 + n];
  } else if(b == 4512){
    gstat[t] = 0.f; gstat[t+256] = 0.f;      // zero 8x32x2 replica stats
    if(t < 91) wlat[t] = cosf(lat[t]);
    __syncthreads();
    if(t == 0){
      float dlat = lat[1]-lat[0];
      float s4 = sinf(dlat*0.25f);
      float pw = s4*s4 / sinf(dlat*0.5f);
      if(wlat[0]  < 0.001f) wlat[0]  = pw;
      if(wlat[90] < 0.001f) wlat[90] = pw;
    }
  } else {
    // modulation tables, transposed out[(h*192+d)][m]
    int b2 = b - 4513;
    const float* coord; const float* freqs; const float* W; float* out;
    int h, m, nm, nk, periodic;
    if(b2 < 1440){ h=b2/180; m=b2%180; nm=180; nk=64; periodic=1; coord=lon; freqs=flong; W=wlong; out=modul; }
    else         { int b3=b2-1440; h=b3/91; m=b3%91; nm=91; nk=32; periodic=0; coord=lat; freqs=flat; W=wlatm; out=modua; }
    float dist = fabsf(coord[m] - coord[0]);
    if(periodic && dist > PI_F) dist = 2.f*PI_F - dist;
    float d = dist + 1e-5f;
    if(t < nk) basis[t] = 0.7978845608028654f * sinf(freqs[t]*d/PI_F) / d;
    __syncthreads();
    if(t < 192){
      float s=0.f;
      for(int k=0;k<nk;k++) s += basis[k]*W[(size_t)(k*8+h)*192+t];
      out[((size_t)h*192 + t)*nm + m] = s;
    }
  }
}

// ---------------- GN1 stats (8-replica atomics) + bf16 cast of u_src (2048 blocks) ----------------
__global__ __launch_bounds__(256) void gn1cast_k(const float* __restrict__ x,
                                                 __bf16* __restrict__ xa,
                                                 float* __restrict__ gstat, int npos){
  int c = threadIdx.x;
  float s=0.f, q=0.f;
  for(int p=blockIdx.x; p<npos; p+=gridDim.x){
    float v = x[p*256 + c];
    xa[p*256 + c] = (__bf16)v;
    s += v; q += v*v;
  }
  __shared__ float ss[256], sq[256];
  ss[c]=s; sq[c]=q;
  __syncthreads();
  if((c&7)==0){
    float a=0.f,b=0.f;
    #pragma unroll
    for(int k=0;k<8;k++){ a+=ss[c+k]; b+=sq[c+k]; }
    int g=c>>3;
    float* dst = gstat + (blockIdx.x&7)*64 + g*2;
    atomicAdd(dst+0, a);
    atomicAdd(dst+1, b);
  }
}

// ---------------- fold GN1 into W1 (folds the replica stats itself) ----------------
__global__ __launch_bounds__(256) void w1fix_k(const float* __restrict__ w1,
                                               const float* __restrict__ b1,
                                               const float* __restrict__ gstat,
                                               const float* __restrict__ gw,
                                               const float* __restrict__ gb,
                                               __bf16* __restrict__ wt1,
                                               float* __restrict__ b1p){
  __shared__ float st[64];
  int n = blockIdx.x, c = threadIdx.x;
  if(c < 64){
    float v = 0.f;
    #pragma unroll
    for(int k=0;k<8;k++) v += gstat[k*64 + c];
    st[c] = v;
  }
  __syncthreads();
  int g = c>>3;
  float m = st[g*2+0]*(1.f/131040.f);
  float var = st[g*2+1]*(1.f/131040.f) - m*m;
  float r = rsqrtf(var+1e-5f);
  float s = r*gw[c];
  float t = gb[c] - m*s;
  float w = w1[(size_t)c*1024 + n];
  wt1[(size_t)n*256 + c] = (__bf16)(s*w);
  __shared__ float red[256];
  red[c] = t*w; __syncthreads();
  for(int stp=128; stp>0; stp>>=1){ if(c<stp) red[c]+=red[c+stp]; __syncthreads(); }
  if(c==0) b1p[n] = b1[n] + red[0];
}

// ---------------- fold GN2 into mh_w ----------------
__global__ __launch_bounds__(256) void w3fix_k(const float* __restrict__ mhw,
                                               const float* __restrict__ part2,
                                               const float* __restrict__ gw,
                                               const float* __restrict__ gb,
                                               __bf16* __restrict__ wt3,
                                               float* __restrict__ b3){
  __shared__ float st[16];
  __shared__ float ps[256], pq[256];
  int n = blockIdx.x, t = threadIdx.x;
  {
    int g = t & 7, ch = t >> 3;
    float s=0.f,q=0.f;
    for(int i=ch; i<91; i+=32){
      s += part2[(g*91+i)*2+0];
      q += part2[(g*91+i)*2+1];
    }
    ps[t]=s; pq[t]=q;
    __syncthreads();
    if(t<8){
      float a=0.f,bq=0.f;
      #pragma unroll
      for(int c=0;c<32;c++){ a+=ps[c*8+t]; bq+=pq[c*8+t]; }
      float m = a*(1.f/1048320.f);
      float v = bq*(1.f/1048320.f) - m*m;
      st[t*2+0]=m; st[t*2+1]=rsqrtf(v+1e-5f);
    }
    __syncthreads();
  }
  float bp=0.f;
  #pragma unroll
  for(int l=0;l<2;l++){
    int cc = t + l*256;
    int g = cc>>6;
    float m = st[g*2+0], r = st[g*2+1];
    float s = r*gw[cc];
    float tt = gb[cc] - m*s;
    float w = mhw[(size_t)cc*256 + n];
    wt3[(size_t)n*512 + cc] = (__bf16)(s*w);
    bp += tt*w;
  }
  __shared__ float red[256];
  red[t]=bp; __syncthreads();
  for(int stp=128;stp>0;stp>>=1){ if(t<stp) red[t]+=red[t+stp]; __syncthreads(); }
  if(t==0) b3[n]=red[0];
}

// ---------------- MFMA bf16 GEMM: 512 thr / 8 waves, BK=32, 3-buffer depth-2 TWO-BARRIER pipeline ----------------
// (structure validated round 8: B1 = counted-vmcnt DMA-landed; B2 = lgkmcnt(0) reads-executed)
template<int ACT, int OUTMODE>
__global__ __launch_bounds__(512) void gemm_ld(const __bf16* __restrict__ A,
                                               const __bf16* __restrict__ Bt,
                                               const float* __restrict__ bias,
                                               void* __restrict__ Cp,
                                               __bf16* __restrict__ VB,
                                               __bf16* __restrict__ UM,
                                               int M, int N, int K)
{
  __shared__ __bf16 smem[24576];   // 3 x (As[128][32] | Bs[128][32]) = 48KB; C-stage reuses 32KB
  __bf16* Asb = smem;              // [3][128][32]
  __bf16* Bsb = smem + 12288;      // [3][128][32]
  const int tid  = threadIdx.x;
  const int lane = tid & 63, wave = tid >> 6;
  const int row0 = blockIdx.x*128, col0 = blockIdx.y*128;
  const int lrow = lane >> 2;                       // 16 rows per wave-load
  const int csw  = ((lane&3) ^ ((lane>>3)&3)) * 8;  // swizzled source chunk
  const int wr = (wave >> 2)*64, wc = (wave & 3)*32;
  const int m16 = lane & 15, quad = lane >> 4;
  const int pa = (quad ^ ((m16>>1)&3)) * 8;         // swizzled read chunk

  const __bf16* Ag = A  + (size_t)(row0 + wave*16 + lrow)*K + csw;
  const __bf16* Bg = Bt + (size_t)(col0 + wave*16 + lrow)*K + csw;

  floatx4 acc[4][2];
  #pragma unroll
  for(int i=0;i<4;i++)
    #pragma unroll
    for(int j=0;j<2;j++) acc[i][j] = (floatx4)0.f;

  const int kiters = K >> 5;
  // prologue: issue iters 0 and 1 into buffers 0,1 (2 loads/thread each)
  gl_lds16(Ag, Asb + wave*512);
  gl_lds16(Bg, Bsb + wave*512);
  Ag += 32; Bg += 32;
  if(kiters > 1){
    gl_lds16(Ag, Asb + 4096 + wave*512);
    gl_lds16(Bg, Bsb + 4096 + wave*512);
    Ag += 32; Bg += 32;
  }

  int rd = 0;   // buffer index holding iter kk
  for(int kk=0; kk<kiters; kk++){
    // prefetch iter kk+2 into buf (kk+2)%3 == (kk-1)%3 — safe: B2 of iter kk-1 passed
    if(kk+2 < kiters){
      int pf = rd + 2; if(pf >= 3) pf -= 3;
      gl_lds16(Ag, Asb + pf*4096 + wave*512);
      gl_lds16(Bg, Bsb + pf*4096 + wave*512);
      Ag += 32; Bg += 32;
    }
    // drain only buf-kk's 2 loads; keep newer ones in flight
    if(kk+2 < kiters)      asm volatile("s_waitcnt vmcnt(4)" ::: "memory");
    else if(kk+1 < kiters) asm volatile("s_waitcnt vmcnt(2)" ::: "memory");
    else                   asm volatile("s_waitcnt vmcnt(0)" ::: "memory");
    __builtin_amdgcn_sched_barrier(0);
    __builtin_amdgcn_s_barrier();        // B1: buf kk ready for all waves
    const int cur = rd*4096;
    bf16x8 af[4], bfv[2];
    #pragma unroll
    for(int ti=0;ti<4;ti++) af[ti]  = *(const bf16x8*)&Asb[cur + (wr + ti*16 + m16)*32 + pa];
    #pragma unroll
    for(int tj=0;tj<2;tj++) bfv[tj] = *(const bf16x8*)&Bsb[cur + (wc + tj*16 + m16)*32 + pa];
    #pragma unroll
    for(int ti=0;ti<4;ti++)
      #pragma unroll
      for(int tj=0;tj<2;tj++)
        acc[ti][tj] = __builtin_amdgcn_mfma_f32_16x16x32_bf16(af[ti], bfv[tj], acc[ti][tj], 0,0,0);
    asm volatile("s_waitcnt lgkmcnt(0)" ::: "memory");
    __builtin_amdgcn_sched_barrier(0);
    __builtin_amdgcn_s_barrier();        // B2: all waves' reads of buf kk executed
    rd++; if(rd >= 3) rd = 0;
  }

  if(OUTMODE==0){
    // direct fp32 stores (64B runs per 16-col fragment)
    #pragma unroll
    for(int ti=0;ti<4;ti++){
      #pragma unroll
      for(int reg=0;reg<4;reg++){
        int gr = row0 + wr + ti*16 + quad*4 + reg;
        if(gr >= M) continue;
        #pragma unroll
        for(int tj=0;tj<2;tj++){
          int gc = col0 + wc + tj*16 + m16;
          float v = acc[ti][tj][reg];
          if(bias) v += bias[gc];
          ((float*)Cp)[(size_t)gr*N + gc] = v;
        }
      }
    }
  } else {
    // stage bf16 tile in smem (K-loop buffers dead after final B2; vmcnt/lgkmcnt drained)
    #pragma unroll
    for(int ti=0;ti<4;ti++){
      #pragma unroll
      for(int reg=0;reg<4;reg++){
        int r = wr + ti*16 + quad*4 + reg;
        #pragma unroll
        for(int tj=0;tj<2;tj++){
          int c = wc + tj*16 + m16;
          float v = acc[ti][tj][reg];
          if(bias) v += bias[col0 + c];
          if(ACT==1) v = gelu_tanh(v);
          smem[r*128 + c] = (__bf16)v;
        }
      }
    }
    __syncthreads();
    if(OUTMODE==1){
      for(int idx=tid; idx<2048; idx+=512){
        int r = idx>>4, ch = (idx&15)*8;
        int gr = row0 + r;
        if(gr < M)
          *(bf16x8*)((__bf16*)Cp + (size_t)gr*N + col0 + ch) = *(const bf16x8*)&smem[r*128 + ch];
      }
    } else if(col0 < 512){
      for(int idx=tid; idx<2048; idx+=512){
        int r = idx>>4, ch = (idx&15)*8;
        int gr = row0 + r;
        if(gr < M){
          int jj = gr/180, mm = gr - jj*180;
          int gc = col0 + ch, hh = gc>>6, cc = gc&63;
          *(bf16x8*)&VB[(((size_t)(hh*180+mm)*91)+jj)*64 + cc] = *(const bf16x8*)&smem[r*128 + ch];
        }
      }
    } else {
      for(int idx=tid; idx<2048; idx+=512){
        int r = idx>>4, ch = (idx&15)*8;
        int gr = row0 + r;
        if(gr < M)
          *(bf16x8*)&UM[(size_t)gr*256 + (col0-512) + ch] = *(const bf16x8*)&smem[r*128 + ch];
      }
    }
  }
}

// ---------------- merged mean + pooling MLP: 1024 threads/row ----------------
__global__ __launch_bounds__(1024) void mpool_k(
    const __bf16* __restrict__ um, const float* __restrict__ wlat,
    const float* __restrict__ tl_inw, const float* __restrict__ tl_lnw, const float* __restrict__ tl_lnb,
    const float* __restrict__ tl_w1, const float* __restrict__ tl_b1,
    const float* __restrict__ tl_w2, const float* __restrict__ tl_b2,
    const float* __restrict__ ta_inw, const float* __restrict__ ta_lnw, const float* __restrict__ ta_lnb,
    const float* __restrict__ ta_w1, const float* __restrict__ ta_b1,
    const float* __restrict__ ta_w2, const float* __restrict__ ta_b2,
    float* __restrict__ ulsrc, float* __restrict__ uasrc){
  __shared__ float part[32][256];        // 32KB; reused as p4[4][256] + p4b[4][256]
  __shared__ float xs[256], xn[256], g[256];
  __shared__ float wsum[4], wsq[4];
  int b = blockIdx.x, t = threadIdx.x;
  int lane = t & 63, wave = t >> 6;
  const int longp = (b < 180);
  int r = longp ? b : b-180;

  const float* inw = longp ? tl_inw : ta_inw;
  const float* lnw = longp ? tl_lnw : ta_lnw;
  const float* lnb = longp ? tl_lnb : ta_lnb;
  const float* w1  = longp ? tl_w1  : ta_w1;
  const float* b1  = longp ? tl_b1  : ta_b1;
  const float* w2  = longp ? tl_w2  : ta_w2;
  const float* b2  = longp ? tl_b2  : ta_b2;
  float*       out = longp ? ulsrc  : uasrc;

  // ---- mean phase: 32-way slice of reduction axis, bf16x8 (16B) loads ----
  int vec = (t & 31) * 8;   // channel-chunk base
  int sub = t >> 5;         // 0..31 slice
  float acc[8] = {0.f,0.f,0.f,0.f,0.f,0.f,0.f,0.f};
  if(longp){
    for(int j=sub; j<91; j+=32){
      bf16x8 v = *(const bf16x8*)&um[((size_t)(j*180+b))*256 + vec];
      #pragma unroll
      for(int e=0;e<8;e++) acc[e] += (float)v[e];
    }
  } else {
    const __bf16* base = um + (size_t)r*180*256;
    for(int m=sub; m<180; m+=32){
      bf16x8 v = *(const bf16x8*)&base[(size_t)m*256 + vec];
      #pragma unroll
      for(int e=0;e<8;e++) acc[e] += (float)v[e];
    }
  }
  #pragma unroll
  for(int e=0;e<8;e++) part[sub][vec+e] = acc[e];
  __syncthreads();
  if(t < 256){
    float s = 0.f;
    #pragma unroll
    for(int k=0;k<32;k++) s += part[k][t];
    xs[t] = s * (longp ? (1.0f/91.0f) : (1.0f/180.0f));
  }
  __syncthreads();   // xs ready; part reads done -> p4 reuse safe

  // ---- phase y: y = xs @ inw, 4-way c-split ----
  float* p4  = &part[0][0];        // [4][256]
  float* p4b = &part[4][0];        // [4][256]
  int q = t >> 8;                  // 0..3 c-chunk
  int o = t & 255;                 // output index
  {
    float yp = 0.f;
    #pragma unroll 8
    for(int c=q*64; c<q*64+64; c++) yp += xs[c]*inw[c*256+o];
    p4[q*256+o] = yp;
  }
  __syncthreads();

  // ---- LN (threads 0..255, shuffle butterfly) ----
  if(t < 256){
    float y = p4[t] + p4[256+t] + p4[512+t] + p4[768+t];
    if(!longp) y *= wlat[r];
    float s = y, qq = y*y;
    #pragma unroll
    for(int off=32; off>0; off>>=1){
      s  += __shfl_xor(s,  off, 64);
      qq += __shfl_xor(qq, off, 64);
    }
    if(lane==0){ wsum[wave]=s; wsq[wave]=qq; }
    xn[t] = y;   // stash y; finish after stats visible
  }
  __syncthreads();
  if(t < 256){
    float s  = wsum[0]+wsum[1]+wsum[2]+wsum[3];
    float qq = wsq[0]+wsq[1]+wsq[2]+wsq[3];
    float m  = s*(1.f/256.f);
    float var = qq*(1.f/256.f) - m*m;
    xn[t] = (xn[t]-m)*rsqrtf(var+1e-5f)*lnw[t] + lnb[t];
  }
  __syncthreads();

  // ---- phase h: s1,s2 = xn @ w1 (512 outs), 4-way c-split ----
  {
    float h1 = 0.f, h2 = 0.f;
    #pragma unroll 8
    for(int c=q*64; c<q*64+64; c++){
      float xv = xn[c];
      h1 += xv*w1[c*512+o];
      h2 += xv*w1[c*512+256+o];
    }
    p4[q*256+o]  = h1;
    p4b[q*256+o] = h2;
  }
  __syncthreads();
  if(t < 256){
    float s1 = p4[t]+p4[256+t]+p4[512+t]+p4[768+t] + b1[t];
    float s2 = p4b[t]+p4b[256+t]+p4b[512+t]+p4b[768+t] + b1[256+t];
    g[t] = gelu_tanh(s1)*s2;
  }
  __syncthreads();

  // ---- phase o: out = g @ w2, 4-way c-split ----
  {
    float op = 0.f;
    #pragma unroll 8
    for(int c=q*64; c<q*64+64; c++) op += g[c]*w2[c*256+o];
    p4[q*256+o] = op;
  }
  __syncthreads();
  if(t < 256)
    out[r*256+t] = p4[t]+p4[256+t]+p4[512+t]+p4[768+t] + b2[t];
}

// ---------------- k-projection, r-tiled: out[j][r0..r0+6] (28B runs per thread) ----------------
__global__ __launch_bounds__(256) void kproj_k(const float* __restrict__ ulsrc,
                                               const float* __restrict__ uasrc,
                                               const float* __restrict__ wlong,
                                               const float* __restrict__ wlatk,
                                               float* __restrict__ klkl,
                                               float* __restrict__ klka){
  int rt = blockIdx.x, jc = blockIdx.y, t = threadIdx.x;
  const int longp = (rt < 26);
  int r0 = (longp ? rt : rt-26) * 7;
  int R  = longp ? 180 : 91;
  int nr = R - r0; if(nr > 7) nr = 7;
  const float* X = longp ? ulsrc : uasrc;
  const float* W = longp ? wlong : wlatk;
  float* out = longp ? klkl : klka;
  __shared__ float xs[7][256];
  for(int idx=t; idx<nr*256; idx+=256)
    xs[idx>>8][idx&255] = X[(size_t)(r0 + (idx>>8))*256 + (idx&255)];
  __syncthreads();
  int j = jc*256 + t;
  float acc[7] = {0.f,0.f,0.f,0.f,0.f,0.f,0.f};
  const float* wp = W + j;
  #pragma unroll 4
  for(int c=0; c<256; c++){
    float wv = wp[(size_t)c*1536];
    #pragma unroll
    for(int rr=0; rr<7; rr++) acc[rr] += xs[rr][c]*wv;
  }
  float* op = out + (size_t)j*R + r0;
  for(int rr=0; rr<nr; rr++) op[rr] = acc[rr];
}

// ---------------- merged low-rank kernels, 2 query-rows per block (shared kp stream) ----------------
__global__ __launch_bounds__(256) void lrk2_k(const float* __restrict__ qlong,
                                              const float* __restrict__ qlat,
                                              const float* __restrict__ klkl,
                                              const float* __restrict__ klka,
                                              const float* __restrict__ modul,
                                              const float* __restrict__ modua,
                                              const float* __restrict__ wlat,
                                              __bf16* __restrict__ kbg,
                                              __bf16* __restrict__ kbl){
  int b = blockIdx.x, t = threadIdx.x;
  const float* qry; const float* kt; const float* mt; const float* js; __bf16* out;
  int h, i0, n, pitch; float scale;
  if(b < 720){ h=b/90; int p=b%90; i0=2*p; n=180; pitch=192; qry=qlong; kt=klkl; mt=modul; js=nullptr; out=kbg; scale=2.f*PI_F/180.f; }
  else        { int b2=b-720; h=b2/46; int p=b2%46; i0=2*p; n=91; pitch=96; qry=qlat; kt=klka; mt=modua; js=wlat; out=kbl; scale=PI_F/91.f; }
  int i1 = i0+1;
  const int has1 = (i1 < n);
  int i1c = has1 ? i1 : i0;
  __shared__ float qs[2][192];
  for(int idx=t; idx<384; idx+=256){
    int row = (idx >= 192);
    int d = idx - row*192;
    int ii = row ? i1c : i0;
    qs[row][d] = qry[(size_t)ii*1536 + h*192 + d];
  }
  __syncthreads();
  int j = t;
  if(j < n){
    int m0 = abs(i0 - j);
    int m1 = abs(i1c - j);
    const float* kp = kt + (size_t)h*192*n;
    const float* mp = mt + (size_t)h*192*n;
    float s0=0.f, s1=0.f;
    #pragma unroll 4
    for(int d=0; d<192; d++){
      float kv = kp[(size_t)d*n + j];
      s0 += qs[0][d]*kv*mp[(size_t)d*n + m0];
      s1 += qs[1][d]*kv*mp[(size_t)d*n + m1];
    }
    s0 = (s0>=0.f) ? s0 : 0.2f*s0;
    if(js) s0 *= js[j];
    out[((size_t)h*pitch + i0)*pitch + j] = (__bf16)(s0*scale);
    if(has1){
      s1 = (s1>=0.f) ? s1 : 0.2f*s1;
      if(js) s1 *= js[j];
      out[((size_t)h*pitch + i1)*pitch + j] = (__bf16)(s1*scale);
    }
  }
}

// ---------------- apply1 MFMA: per (h,m): C[91,64] = klat[h](91x91) @ V(91x64) ----------------
__global__ __launch_bounds__(256) void apply1_mfma(const __bf16* __restrict__ Kl,
                                                   const __bf16* __restrict__ vbf,
                                                   __bf16* __restrict__ u1){
  int h = blockIdx.x / 180, m = blockIdx.x % 180;
  __shared__ __bf16 vst[64][104];           // 6656 elems; reused as ost[91][72]=6552
  int t = threadIdx.x;
  const __bf16* src = vbf + ((size_t)(h*180+m)*91)*64;
  for(int idx=t; idx<91*64; idx+=256){
    int j = idx>>6, c = idx&63;
    vst[c][j] = src[idx];
  }
  for(int idx=t; idx<64*13; idx+=256){
    int c = idx/13, j = 91 + idx - (idx/13)*13;
    vst[c][j] = (__bf16)0.f;
  }
  __syncthreads();
  int lane = t & 63, wave = t>>6;
  int m16 = lane & 15, quad = lane>>4;
  floatx4 acc[6];
  #pragma unroll
  for(int i=0;i<6;i++) acc[i]=(floatx4)0.f;
  const __bf16* Ab = Kl + (size_t)h*96*96;
  #pragma unroll
  for(int kc=0; kc<3; kc++){
    bf16x8 bfrag = *(const bf16x8*)&vst[wave*16 + m16][kc*32 + quad*8];
    #pragma unroll
    for(int ti=0;ti<6;ti++){
      bf16x8 afrag = *(const bf16x8*)&Ab[(size_t)(ti*16+m16)*96 + kc*32 + quad*8];
      acc[ti] = __builtin_amdgcn_mfma_f32_16x16x32_bf16(afrag, bfrag, acc[ti], 0,0,0);
    }
  }
  __syncthreads();                          // vst reads done; reuse as ost
  __bf16* ost = &vst[0][0];
  int c = wave*16 + m16;
  #pragma unroll
  for(int ti=0;ti<6;ti++){
    #pragma unroll
    for(int reg=0;reg<4;reg++){
      int i = ti*16 + quad*4 + reg;
      if(i<91) ost[i*72 + c] = (__bf16)acc[ti][reg];
    }
  }
  __syncthreads();
  __bf16* dst = u1 + (((size_t)(h*91)*180)+m)*64;
  for(int idx=t; idx<91*8; idx+=256){
    int i = idx>>3, cc = idx&7;
    *(bf16x8*)(dst + (size_t)i*180*64 + cc*8) = *(const bf16x8*)&ost[i*72 + cc*8];
  }
}

// ---------------- apply2 MFMA: A2 bf16 [pos][512] via staged 128B stores + GN2 partials ----------------
__global__ __launch_bounds__(256) void apply2_mfma(const __bf16* __restrict__ Kg,
                                                   const __bf16* __restrict__ u1,
                                                   __bf16* __restrict__ a2,
                                                   float* __restrict__ part2){
  int h = blockIdx.x / 91, i = blockIdx.x % 91;
  __shared__ __bf16 vst[64][208];           // 13312 elems; reused as ost[180][72]=12960
  __shared__ float rs[256], rq[256];
  int t = threadIdx.x;
  const __bf16* src = u1 + ((size_t)(h*91+i)*180)*64;
  for(int idx=t; idx<180*64; idx+=256){
    int m = idx>>6, c = idx&63;
    vst[c][m] = src[idx];
  }
  for(int idx=t; idx<64*28; idx+=256){
    int c = idx/28, m = 180 + idx - (idx/28)*28;
    vst[c][m] = (__bf16)0.f;
  }
  __syncthreads();
  int lane = t&63, wave = t>>6;
  int m16 = lane&15, quad = lane>>4;
  floatx4 acc[12];
  #pragma unroll
  for(int l=0;l<12;l++) acc[l]=(floatx4)0.f;
  const __bf16* Ab = Kg + (size_t)h*192*192;
  for(int kc=0; kc<6; kc++){
    bf16x8 bfrag = *(const bf16x8*)&vst[wave*16+m16][kc*32 + quad*8];
    #pragma unroll
    for(int tl=0; tl<12; tl++){
      bf16x8 afrag = *(const bf16x8*)&Ab[(size_t)(tl*16+m16)*192 + kc*32 + quad*8];
      acc[tl] = __builtin_amdgcn_mfma_f32_16x16x32_bf16(afrag, bfrag, acc[tl], 0,0,0);
    }
  }
  __syncthreads();                          // vst reads done; reuse as ost
  __bf16* ost = &vst[0][0];
  int c = wave*16+m16;
  float s=0.f, q=0.f;
  #pragma unroll
  for(int tl=0; tl<12; tl++){
    #pragma unroll
    for(int reg=0; reg<4; reg++){
      int l = tl*16 + quad*4 + reg;
      if(l<180){
        float v = acc[tl][reg];
        ost[l*72 + c] = (__bf16)v;
        s += v; q += v*v;
      }
    }
  }
  rs[t]=s; rq[t]=q;
  __syncthreads();
  for(int st=128; st>0; st>>=1){ if(t<st){ rs[t]+=rs[t+st]; rq[t]+=rq[t+st]; } __syncthreads(); }
  if(t==0){ part2[blockIdx.x*2+0]=rs[0]; part2[blockIdx.x*2+1]=rq[0]; }
  __bf16* dst = a2 + (size_t)i*180*512 + h*64;
  for(int idx=t; idx<180*8; idx+=256){
    int l = idx>>3, cc = idx&7;
    *(bf16x8*)(dst + (size_t)l*512 + cc*8) = *(const bf16x8*)&ost[l*72 + cc*8];
  }
}

// ---------------------------------------------------------------------------
extern "C" void kernel_launch(void* const* d_in, const int* in_sizes, int n_in,
                              void* d_out, int out_size, void* d_ws, size_t ws_size,
                              hipStream_t stream){
  const float* u_src      = (const float*)d_in[0];
  const float* u_lat_qry  = (const float*)d_in[1];
  const float* u_long_qry = (const float*)d_in[2];
  const float* lat = (const float*)d_in[3];
  const float* lon = (const float*)((in_sizes[4]==180)? d_in[4] : d_in[5]);
  const float* cm_gn_w = (const float*)d_in[7];
  const float* cm_gn_b = (const float*)d_in[8];
  const float* cm_w1   = (const float*)d_in[9];
  const float* cm_b1   = (const float*)d_in[10];
  const float* cm_w2   = (const float*)d_in[11];
  const float* cm_b2   = (const float*)d_in[12];
  const float* tl_in_w = (const float*)d_in[13];
  const float* tl_ln_w = (const float*)d_in[14];
  const float* tl_ln_b = (const float*)d_in[15];
  const float* tl_w1   = (const float*)d_in[16];
  const float* tl_b1   = (const float*)d_in[17];
  const float* tl_w2   = (const float*)d_in[18];
  const float* tl_b2   = (const float*)d_in[19];
  const float* ta_in_w = (const float*)d_in[20];
  const float* ta_ln_w = (const float*)d_in[21];
  const float* ta_ln_b = (const float*)d_in[22];
  const float* ta_w1   = (const float*)d_in[23];
  const float* ta_b1   = (const float*)d_in[24];
  const float* ta_w2   = (const float*)d_in[25];
  const float* ta_b2   = (const float*)d_in[26];
  const float* klong_wk= (const float*)d_in[27];
  const float* klat_wk = (const float*)d_in[28];
  const float* pe_long_freq = (const float*)d_in[29];
  const float* pe_long_w    = (const float*)d_in[30];
  const float* pe_lat_freq  = (const float*)d_in[31];
  const float* pe_lat_w     = (const float*)d_in[32];
  const float* mh_gn_w = (const float*)d_in[33];
  const float* mh_gn_b = (const float*)d_in[34];
  const float* mh_w    = (const float*)d_in[35];

  float* ws = (float*)d_ws;
  const size_t OFF_GN1    = 0;          // 512  (8 replicas x 32 groups x {s,q})
  const size_t OFF_WLAT   = 1024;       // 91
  const size_t OFF_ULSRC  = 2048;       // 46080 fp32 [180][256]
  const size_t OFF_UASRC  = 48128;      // 23296 fp32 [91][256]
  const size_t OFF_KLKL   = 102400;     // 276480 fp32 kprojT long [1536][180]
  const size_t OFF_KLKA   = 378880;     // 139776 fp32 kprojT lat  [1536][91]
  const size_t OFF_MODUL  = 518656;     // 276480 fp32 modT long [1536][180]
  const size_t OFF_MODUA  = 795136;     // 139776 fp32 modT lat  [1536][91]
  const size_t OFF_KBL    = 934912;     // bf16 8*96*96   -> 36864 f
  const size_t OFF_KBG    = 971776;     // bf16 8*192*192 -> 147456 f -> ends 1119232
  const size_t OFF_PART2  = 1119232;    // 1456
  const size_t OFF_B1P    = 1120688;    // 1024
  const size_t OFF_B3     = 1121712;    // 256
  const size_t OFF_WT1    = 1122048;    // bf16 [1024][256] -> 131072 f
  const size_t OFF_WT2    = 1253120;    // bf16 [768][1024] -> 393216 f
  const size_t OFF_WT3    = 1646336;    // bf16 [256][512]  -> 65536 f -> ends 1711872
  const size_t OFF_VBF    = 1711872;    // bf16 [8][180][91][64] -> 4193280 f
  const size_t OFF_A2     = 1711872;    // bf16 [16380][512] (reuses VBF post-apply1)
  const size_t OFF_UMID   = 5905152;    // bf16 [16380][256] -> 2096640 f
  const size_t OFF_H1     = 8001792;    // bf16 16380x1024 -> 8386560 f
  const size_t OFF_U1     = 8001792;    // bf16 (reuses H1)
  const size_t OFF_A1     = 16388352;   // bf16 16380x256 -> ends 18484992 (~74 MB)

  const int NPOS = 16380;

  // 1) prep2 (zfill + wcvt w2 + wlat + stat-zero + modulation tables)
  prep2_k<<<6681,256,0,stream>>>(cm_w2, (__bf16*)(ws+OFF_WT2), (__bf16*)(ws+OFF_KBL),
      lat, ws+OFF_WLAT, ws+OFF_GN1,
      lon, pe_long_freq, pe_lat_freq, pe_long_w, pe_lat_w,
      ws+OFF_MODUL, ws+OFF_MODUA);

  // 2) GN1 stats (replica atomics) + bf16 cast of u_src
  gn1cast_k<<<2048,256,0,stream>>>(u_src, (__bf16*)(ws+OFF_A1), ws+OFF_GN1, NPOS);

  // 3) fold GN1 into W1 (folds replica stats in-block)
  w1fix_k<<<1024,256,0,stream>>>(cm_w1, cm_b1, ws+OFF_GN1, cm_gn_w, cm_gn_b,
      (__bf16*)(ws+OFF_WT1), ws+OFF_B1P);

  // 4) h1 = gelu(A1 @ W1' + b1')  [16380 x 1024] bf16   (512-thread, 8-wave, 2-barrier pipe)
  gemm_ld<1,1><<<dim3(128,8),512,0,stream>>>((const __bf16*)(ws+OFF_A1),
      (const __bf16*)(ws+OFF_WT1), ws+OFF_B1P, ws+OFF_H1, nullptr, nullptr, NPOS, 1024, 256);

  // 5) u2 = h1 @ W2 + b2: cols<512 -> vbf bf16; cols>=512 -> umid bf16
  gemm_ld<0,2><<<dim3(128,6),512,0,stream>>>((const __bf16*)(ws+OFF_H1),
      (const __bf16*)(ws+OFF_WT2), cm_b2, nullptr, (__bf16*)(ws+OFF_VBF),
      (__bf16*)(ws+OFF_UMID), NPOS, 768, 1024);

  // 6) merged mean + pooling MLPs (1024 threads/row)
  mpool_k<<<271,1024,0,stream>>>((const __bf16*)(ws+OFF_UMID), ws+OFF_WLAT,
      tl_in_w, tl_ln_w, tl_ln_b, tl_w1, tl_b1, tl_w2, tl_b2,
      ta_in_w, ta_ln_w, ta_ln_b, ta_w1, ta_b1, ta_w2, ta_b2,
      ws+OFF_ULSRC, ws+OFF_UASRC);

  // 7) k-projections, r-tiled coalesced stores
  kproj_k<<<dim3(39,6),256,0,stream>>>(ws+OFF_ULSRC, ws+OFF_UASRC, klong_wk, klat_wk,
      ws+OFF_KLKL, ws+OFF_KLKA);

  // 8) merged low-rank kernels (2 rows/block) -> padded bf16
  lrk2_k<<<1088,256,0,stream>>>(u_long_qry, u_lat_qry, ws+OFF_KLKL, ws+OFF_KLKA,
      ws+OFF_MODUL, ws+OFF_MODUA, ws+OFF_WLAT, (__bf16*)(ws+OFF_KBG), (__bf16*)(ws+OFF_KBL));

  // 9) kernel application (MFMA, vectorized epilogues); apply2 emits A2 + GN2 partials
  apply1_mfma<<<8*180,256,0,stream>>>((const __bf16*)(ws+OFF_KBL), (const __bf16*)(ws+OFF_VBF),
      (__bf16*)(ws+OFF_U1));
  apply2_mfma<<<8*91, 256,0,stream>>>((const __bf16*)(ws+OFF_KBG), (const __bf16*)(ws+OFF_U1),
      (__bf16*)(ws+OFF_A2), ws+OFF_PART2);

  // 10) fold GN2 into mh_w, then final projection
  w3fix_k<<<256,256,0,stream>>>(mh_w, ws+OFF_PART2, mh_gn_w, mh_gn_b,
      (__bf16*)(ws+OFF_WT3), ws+OFF_B3);
  gemm_ld<0,0><<<dim3(128,2),512,0,stream>>>((const __bf16*)(ws+OFF_A2),
      (const __bf16*)(ws+OFF_WT3), ws+OFF_B3, (float*)d_out, nullptr, nullptr, NPOS, 256, 512);
}